// Round 2
// baseline (543.194 us; speedup 1.0000x reference)
//
#include <hip/hip_runtime.h>
#include <stdint.h>

typedef unsigned short u16;
typedef float f32x4 __attribute__((ext_vector_type(4)));
typedef int   i32x4 __attribute__((ext_vector_type(4)));

__device__ __forceinline__ u16 f2h(float f) {
  _Float16 h = (_Float16)f;           // v_cvt_f16_f32, RNE
  u16 u; __builtin_memcpy(&u, &h, 2); return u;
}
__device__ __forceinline__ float h2f(u16 u) {
  _Float16 h; __builtin_memcpy(&h, &u, 2); return (float)h;
}

// MFMA f16: acc += A*B (16x16x32)
__device__ __forceinline__ void mfma_f16(f32x4& c, i32x4 a, i32x4 b) {
  asm("v_mfma_f32_16x16x32_f16 %0, %1, %2, %0" : "+v"(c) : "v"(a), "v"(b));
}

// ---------------- conversion kernels ----------------
struct alignas(8) US4 { u16 a, b, c, d; };

__global__ void k_conv_hilo(const float* __restrict__ src, u16* __restrict__ hi,
                            u16* __restrict__ lo, int n4) {
  int i = blockIdx.x * blockDim.x + threadIdx.x;
  int stride = gridDim.x * blockDim.x;
  for (; i < n4; i += stride) {
    float4 v = reinterpret_cast<const float4*>(src)[i];
    US4 h, l;
    h.a = f2h(v.x); l.a = f2h(v.x - h2f(h.a));
    h.b = f2h(v.y); l.b = f2h(v.y - h2f(h.b));
    h.c = f2h(v.z); l.c = f2h(v.z - h2f(h.c));
    h.d = f2h(v.w); l.d = f2h(v.w - h2f(h.d));
    reinterpret_cast<US4*>(hi)[i] = h;
    reinterpret_cast<US4*>(lo)[i] = l;
  }
}

__global__ void k_conv_f16(const float* __restrict__ src, u16* __restrict__ dst, int n4) {
  int i = blockIdx.x * blockDim.x + threadIdx.x;
  int stride = gridDim.x * blockDim.x;
  for (; i < n4; i += stride) {
    float4 v = reinterpret_cast<const float4*>(src)[i];
    US4 h;
    h.a = f2h(v.x); h.b = f2h(v.y); h.c = f2h(v.z); h.d = f2h(v.w);
    reinterpret_cast<US4*>(dst)[i] = h;
  }
}

// transpose f32 (B,R,C) -> f16 (B,C,R)
__global__ __launch_bounds__(256)
void k_transpose_f16(const float* __restrict__ src, u16* __restrict__ dst, int R, int C) {
  __shared__ u16 t[32][33];
  const int b = blockIdx.z;
  const float* s = src + (size_t)b * R * C;
  u16* d = dst + (size_t)b * R * C;
  const int c0 = blockIdx.x * 32, r0 = blockIdx.y * 32;
  const int tx = threadIdx.x, ty = threadIdx.y;
#pragma unroll
  for (int j = ty; j < 32; j += 8)
    t[j][tx] = f2h(s[(size_t)(r0 + j) * C + (c0 + tx)]);
  __syncthreads();
#pragma unroll
  for (int j = ty; j < 32; j += 8)
    d[(size_t)(c0 + j) * R + (r0 + tx)] = t[tx][j];
}

// ---------------- softmax (one wave per row), f32 in place + f16 copy ----------------
template<int L>
__global__ __launch_bounds__(256)
void k_softmax(float* __restrict__ io, u16* __restrict__ pb) {
  const int lane = threadIdx.x & 63;
  const size_t r = (size_t)blockIdx.x * 4 + (threadIdx.x >> 6);
  float* row = io + r * L;
  u16* prow = pb + r * L;
  constexpr int NV = L / 64;
  float v[NV];
  float mx = -3.4e38f;
#pragma unroll
  for (int j = 0; j < NV; ++j) { v[j] = row[lane + j * 64]; mx = fmaxf(mx, v[j]); }
#pragma unroll
  for (int s = 32; s; s >>= 1) mx = fmaxf(mx, __shfl_xor(mx, s));
  float sum = 0.f;
#pragma unroll
  for (int j = 0; j < NV; ++j) { v[j] = __expf(v[j] - mx); sum += v[j]; }
#pragma unroll
  for (int s = 32; s; s >>= 1) sum += __shfl_xor(sum, s);
  const float inv = 1.f / sum;
#pragma unroll
  for (int j = 0; j < NV; ++j) {
    float pv = v[j] * inv;
    row[lane + j * 64] = pv;
    prow[lane + j * 64] = f2h(pv);
  }
}

// ---------------- NT MFMA GEMM: C[m,n] = sum_k A[m,k]*B[n,k] ----------------
// XM: 0 = 1-pass f16; 2 = both split hi/lo (3 mfma: ah*bh + al*bh + ah*bl)
// EPI: 0 Cf=acc; 1 Cf+=acc; 2 Cb=f16(acc);
//      3 Facc += (1-sigmoid(G))*acc; 4 Cf = tanh(Facc + sigmoid(G)*acc)
constexpr int BM = 128, BN = 128, BK = 32, LDT = 40;

template<int XM, int EPI>
__global__ __launch_bounds__(256, 2)
void k_gemm_nt(const u16* __restrict__ Ah, const u16* __restrict__ Al,
               const u16* __restrict__ Bh, const u16* __restrict__ Bl,
               int lda, int ldb, long long sA, long long sB,
               float* __restrict__ Cf, u16* __restrict__ Cb,
               int ldc, long long sC,
               const float* __restrict__ G, float* __restrict__ Facc,
               int K)
{
  __shared__ u16 sAh[BM * LDT];
  __shared__ u16 sBh[BN * LDT];
  __shared__ u16 sAl[(XM >= 1) ? BM * LDT : 8];
  __shared__ u16 sBl[(XM >= 2) ? BN * LDT : 8];

  const int tid = threadIdx.x;
  const int lane = tid & 63;
  const int wv = tid >> 6;
  const int wm = wv >> 1, wn = wv & 1;

  const long long b = blockIdx.z;
  const size_t aoff = (size_t)(b * sA) + (size_t)blockIdx.y * BM * lda;
  const size_t boff = (size_t)(b * sB) + (size_t)blockIdx.x * BN * ldb;
  const u16* A0 = Ah + aoff;
  const u16* B0 = Bh + boff;

  const int r0 = tid >> 2;          // staging row (0..63), second chunk at +64
  const int cc = (tid & 3) * 8;     // staging col offset in elems

  f32x4 acc[16];
#pragma unroll
  for (int i = 0; i < 16; ++i) acc[i] = f32x4{0.f, 0.f, 0.f, 0.f};

  const int fr = lane & 15;
  const int kq = (lane >> 4) * 8;

  for (int k0 = 0; k0 < K; k0 += BK) {
    *reinterpret_cast<uint4*>(&sAh[r0 * LDT + cc]) =
        *reinterpret_cast<const uint4*>(A0 + (size_t)r0 * lda + k0 + cc);
    *reinterpret_cast<uint4*>(&sAh[(r0 + 64) * LDT + cc]) =
        *reinterpret_cast<const uint4*>(A0 + (size_t)(r0 + 64) * lda + k0 + cc);
    *reinterpret_cast<uint4*>(&sBh[r0 * LDT + cc]) =
        *reinterpret_cast<const uint4*>(B0 + (size_t)r0 * ldb + k0 + cc);
    *reinterpret_cast<uint4*>(&sBh[(r0 + 64) * LDT + cc]) =
        *reinterpret_cast<const uint4*>(B0 + (size_t)(r0 + 64) * ldb + k0 + cc);
    if constexpr (XM >= 1) {
      const u16* A1 = Al + aoff;
      *reinterpret_cast<uint4*>(&sAl[r0 * LDT + cc]) =
          *reinterpret_cast<const uint4*>(A1 + (size_t)r0 * lda + k0 + cc);
      *reinterpret_cast<uint4*>(&sAl[(r0 + 64) * LDT + cc]) =
          *reinterpret_cast<const uint4*>(A1 + (size_t)(r0 + 64) * lda + k0 + cc);
    }
    if constexpr (XM >= 2) {
      const u16* B1 = Bl + boff;
      *reinterpret_cast<uint4*>(&sBl[r0 * LDT + cc]) =
          *reinterpret_cast<const uint4*>(B1 + (size_t)r0 * ldb + k0 + cc);
      *reinterpret_cast<uint4*>(&sBl[(r0 + 64) * LDT + cc]) =
          *reinterpret_cast<const uint4*>(B1 + (size_t)(r0 + 64) * ldb + k0 + cc);
    }
    __syncthreads();

    i32x4 ah[4], bh[4], al[4], bl[4];
#pragma unroll
    for (int i = 0; i < 4; ++i) {
      ah[i] = *reinterpret_cast<const i32x4*>(&sAh[(wm * 64 + i * 16 + fr) * LDT + kq]);
      bh[i] = *reinterpret_cast<const i32x4*>(&sBh[(wn * 64 + i * 16 + fr) * LDT + kq]);
      if constexpr (XM >= 1)
        al[i] = *reinterpret_cast<const i32x4*>(&sAl[(wm * 64 + i * 16 + fr) * LDT + kq]);
      if constexpr (XM >= 2)
        bl[i] = *reinterpret_cast<const i32x4*>(&sBl[(wn * 64 + i * 16 + fr) * LDT + kq]);
    }

#pragma unroll
    for (int i = 0; i < 4; ++i)
#pragma unroll
      for (int j = 0; j < 4; ++j) {
        mfma_f16(acc[i * 4 + j], ah[i], bh[j]);
        if constexpr (XM >= 1) mfma_f16(acc[i * 4 + j], al[i], bh[j]);
        if constexpr (XM >= 2) mfma_f16(acc[i * 4 + j], ah[i], bl[j]);
      }
    __syncthreads();
  }

  // epilogue: C/D layout col = lane&15, row = (lane>>4)*4 + reg
  const size_t cbse = (size_t)(b * sC);
  const int row0 = blockIdx.y * BM + wm * 64;
  const int col0 = blockIdx.x * BN + wn * 64;
  const int fq = (lane >> 4) * 4;
#pragma unroll
  for (int i = 0; i < 4; ++i) {
#pragma unroll
    for (int j = 0; j < 4; ++j) {
      f32x4 v = acc[i * 4 + j];
      const int c = col0 + j * 16 + fr;
#pragma unroll
      for (int q = 0; q < 4; ++q) {
        const int r = row0 + i * 16 + fq + q;
        const size_t idx = cbse + (size_t)r * ldc + c;
        if constexpr (EPI == 0) {
          Cf[idx] = v[q];
        } else if constexpr (EPI == 1) {
          Cf[idx] += v[q];
        } else if constexpr (EPI == 2) {
          Cb[idx] = f2h(v[q]);
        } else if constexpr (EPI == 3) {
          float g = 1.f / (1.f + __expf(-G[idx]));
          Facc[idx] += (1.f - g) * v[q];
        } else {  // EPI == 4
          float g = 1.f / (1.f + __expf(-G[idx]));
          float x = Facc[idx] + g * v[q];
          float ax = fabsf(x);
          float e = __expf(-2.f * ax);
          float t = (1.f - e) / (1.f + e);
          Cf[idx] = copysignf(t, x);
        }
      }
    }
  }
}

extern "C" void kernel_launch(void* const* d_in, const int* in_sizes, int n_in,
                              void* d_out, int out_size, void* d_ws, size_t ws_size,
                              hipStream_t stream) {
  (void)in_sizes; (void)n_in; (void)out_size; (void)ws_size;
  constexpr int B = 8, T = 1024, S = 1024, St = 512, H = 1024;
  constexpr long long BTH = (long long)B * T * H;
  constexpr long long BSH = (long long)B * S * H;
  constexpr long long BStH = (long long)B * St * H;
  constexpr long long BTS = (long long)B * T * S;
  constexpr long long BTSt = (long long)B * T * St;
  constexpr long long TH = (long long)T * H;

  const float* in_out  = (const float*)d_in[0];
  const float* in_sent = (const float*)d_in[1];
  const float* in_tmpl = (const float*)d_in[2];
  const float* in_Wg   = (const float*)d_in[3];
  const float* in_Ws   = (const float*)d_in[4];
  const float* in_Wt   = (const float*)d_in[5];
  const float* in_Wo   = (const float*)d_in[6];

  float* fus = (float*)d_out;         // (B,T,H)
  float* sw  = fus + BTH;             // (B,T,S) sent_weight
  float* tw  = sw + BTS;              // (B,T,St) template_weight

  // ---- workspace layout (== round-1 footprint, 214 MB) ----
  char* p = (char*)d_ws;
  auto take = [&](long long bytes) { char* q = p; p += bytes; return q; };
  u16* out_hi  = (u16*)take(BTH * 2);
  u16* out_lo  = (u16*)take(BTH * 2);
  u16* sent_hi = (u16*)take(BSH * 2);    // dead after sent-logits -> reused as ctx_s
  u16* sent_lo = (u16*)take(BSH * 2);    // dead after sent-logits -> reused as ctx_t
  u16* tmpl_hi = (u16*)take(BStH * 2);
  u16* tmpl_lo = (u16*)take(BStH * 2);
  u16* sentT   = (u16*)take(BSH * 2);    // (B,H,S) f16
  u16* tmplT   = (u16*)take(BStH * 2);   // (B,H,St) f16
  u16* Wg_b    = (u16*)take((long long)3 * H * H * 2);
  u16* Ws_b    = (u16*)take((long long)H * H * 2);
  u16* Wt_b    = (u16*)take((long long)H * H * 2);
  u16* Wo_b    = (u16*)take((long long)H * H * 2);
  u16* Ps      = (u16*)take(BTS * 2);    // f16 sent weights
  u16* Pt      = (u16*)take(BTSt * 2);   // f16 template weights
  float* g_acc = (float*)take(BTH * 4);
  float* F     = (float*)take(BTH * 4);

  u16* ctx_s = sent_hi;   // (B,T,H) f16, written by PV-sent (after sent-logits)
  u16* ctx_t = sent_lo;   // (B,T,H) f16, written by PV-tmpl

  dim3 thr(256);

  // conversions
  k_conv_hilo<<<2048, 256, 0, stream>>>(in_out,  out_hi,  out_lo,  (int)(BTH / 4));
  k_conv_hilo<<<2048, 256, 0, stream>>>(in_sent, sent_hi, sent_lo, (int)(BSH / 4));
  k_conv_hilo<<<1024, 256, 0, stream>>>(in_tmpl, tmpl_hi, tmpl_lo, (int)(BStH / 4));
  k_conv_f16<<<1024, 256, 0, stream>>>(in_Wg, Wg_b, 3 * H * H / 4);
  k_conv_f16<<<512, 256, 0, stream>>>(in_Ws, Ws_b, H * H / 4);
  k_conv_f16<<<512, 256, 0, stream>>>(in_Wt, Wt_b, H * H / 4);
  k_conv_f16<<<512, 256, 0, stream>>>(in_Wo, Wo_b, H * H / 4);

  // transposes for PV (NT layout)
  k_transpose_f16<<<dim3(H / 32, S / 32, B), dim3(32, 8), 0, stream>>>(in_sent, sentT, S, H);
  k_transpose_f16<<<dim3(H / 32, St / 32, B), dim3(32, 8), 0, stream>>>(in_tmpl, tmplT, St, H);

  // logits (3-pass split f16 for softmax/weight accuracy), straight into d_out
  k_gemm_nt<2, 0><<<dim3(S / BN, T / BM, B), thr, 0, stream>>>(
      out_hi, out_lo, sent_hi, sent_lo, H, H, TH, (long long)S * H,
      sw, nullptr, S, (long long)T * S, nullptr, nullptr, H);
  k_gemm_nt<2, 0><<<dim3(St / BN, T / BM, B), thr, 0, stream>>>(
      out_hi, out_lo, tmpl_hi, tmpl_lo, H, H, TH, (long long)St * H,
      tw, nullptr, St, (long long)T * St, nullptr, nullptr, H);

  // softmax in place + f16 copy
  k_softmax<1024><<<(B * T) / 4, 256, 0, stream>>>(sw, Ps);
  k_softmax<512><<<(B * T) / 4, 256, 0, stream>>>(tw, Pt);

  // PV GEMMs -> ctx (f16), 1-pass
  k_gemm_nt<0, 2><<<dim3(H / BN, T / BM, B), thr, 0, stream>>>(
      Ps, nullptr, sentT, nullptr, S, S, (long long)T * S, (long long)H * S,
      nullptr, ctx_s, H, TH, nullptr, nullptr, S);
  k_gemm_nt<0, 2><<<dim3(H / BN, T / BM, B), thr, 0, stream>>>(
      Pt, nullptr, tmplT, nullptr, St, St, (long long)T * St, (long long)H * St,
      nullptr, ctx_t, H, TH, nullptr, nullptr, St);

  // gate pre-activation z = cat @ Wg^T (3 K-segments, accumulated)
  k_gemm_nt<0, 0><<<dim3(H / BN, T / BM, B), thr, 0, stream>>>(
      ctx_s, nullptr, Wg_b, nullptr, H, 3 * H, TH, 0LL,
      g_acc, nullptr, H, TH, nullptr, nullptr, H);
  k_gemm_nt<0, 1><<<dim3(H / BN, T / BM, B), thr, 0, stream>>>(
      ctx_t, nullptr, Wg_b + H, nullptr, H, 3 * H, TH, 0LL,
      g_acc, nullptr, H, TH, nullptr, nullptr, H);
  k_gemm_nt<0, 1><<<dim3(H / BN, T / BM, B), thr, 0, stream>>>(
      out_hi, nullptr, Wg_b + 2 * H, nullptr, H, 3 * H, TH, 0LL,
      g_acc, nullptr, H, TH, nullptr, nullptr, H);

  // F = output @ Wo^T
  k_gemm_nt<0, 0><<<dim3(H / BN, T / BM, B), thr, 0, stream>>>(
      out_hi, nullptr, Wo_b, nullptr, H, H, TH, 0LL,
      F, nullptr, H, TH, nullptr, nullptr, H);
  // F += (1-sigmoid(z)) * (sent_ctx @ Ws^T)
  k_gemm_nt<0, 3><<<dim3(H / BN, T / BM, B), thr, 0, stream>>>(
      ctx_s, nullptr, Ws_b, nullptr, H, H, TH, 0LL,
      nullptr, nullptr, H, TH, g_acc, F, H);
  // fusion = tanh(F + sigmoid(z) * (tmpl_ctx @ Wt^T)) -> d_out
  k_gemm_nt<0, 4><<<dim3(H / BN, T / BM, B), thr, 0, stream>>>(
      ctx_t, nullptr, Wt_b, nullptr, H, H, TH, 0LL,
      fus, nullptr, H, TH, g_acc, F, H);
}

// Round 4
// 436.737 us; speedup vs baseline: 1.2438x; 1.2438x over previous
//
#include <hip/hip_runtime.h>
#include <stdint.h>

typedef unsigned short u16;
typedef float f32x4 __attribute__((ext_vector_type(4)));
typedef int   i32x4 __attribute__((ext_vector_type(4)));

__device__ __forceinline__ u16 f2h(float f) {
  _Float16 h = (_Float16)f;  // v_cvt_f16_f32, RNE
  u16 u; __builtin_memcpy(&u, &h, 2); return u;
}
__device__ __forceinline__ float h2f(u16 u) {
  _Float16 h; __builtin_memcpy(&h, &u, 2); return (float)h;
}

__device__ __forceinline__ void mfma_f16(f32x4& c, i32x4 a, i32x4 b) {
  asm("v_mfma_f32_16x16x32_f16 %0, %1, %2, %0" : "+v"(c) : "v"(a), "v"(b));
}

// async global->LDS, 16B per lane; LDS dest = wave-uniform base, lane i lands at +i*16B
__device__ __forceinline__ void g2l16(const u16* g, u16* l) {
  __builtin_amdgcn_global_load_lds((const __attribute__((address_space(1))) void*)g,
                                   (__attribute__((address_space(3))) void*)l,
                                   16, 0, 0);
}

struct alignas(8) US4 { u16 a, b, c, d; };

// ---- output: f32 -> f16 hi + lo residual ----
__global__ void k_conv_hilo(const float* __restrict__ src, u16* __restrict__ hi,
                            u16* __restrict__ lo, int n4) {
  int i = blockIdx.x * blockDim.x + threadIdx.x;
  int stride = gridDim.x * blockDim.x;
  for (; i < n4; i += stride) {
    float4 v = reinterpret_cast<const float4*>(src)[i];
    US4 h, l;
    h.a = f2h(v.x); l.a = f2h(v.x - h2f(h.a));
    h.b = f2h(v.y); l.b = f2h(v.y - h2f(h.b));
    h.c = f2h(v.z); l.c = f2h(v.z - h2f(h.c));
    h.d = f2h(v.w); l.d = f2h(v.w - h2f(h.d));
    reinterpret_cast<US4*>(hi)[i] = h;
    reinterpret_cast<US4*>(lo)[i] = l;
  }
}

// ---- 4 weight matrices: f32 -> f16 (1-pass) ----
__global__ void k_conv_w(const float* __restrict__ s_wg, const float* __restrict__ s_ws,
                         const float* __restrict__ s_wt, const float* __restrict__ s_wo,
                         u16* __restrict__ d_wg, u16* __restrict__ d_ws,
                         u16* __restrict__ d_wt, u16* __restrict__ d_wo) {
  constexpr int N1 = 786432;   // 3*1024*1024/4
  constexpr int N2 = 262144;   // 1024*1024/4
  constexpr int total = N1 + 3 * N2;
  int i = blockIdx.x * blockDim.x + threadIdx.x;
  int stride = gridDim.x * blockDim.x;
  for (; i < total; i += stride) {
    const float* s; u16* d; int j;
    if (i < N1)                { s = s_wg; d = d_wg; j = i; }
    else if (i < N1 + N2)      { s = s_ws; d = d_ws; j = i - N1; }
    else if (i < N1 + 2 * N2)  { s = s_wt; d = d_wt; j = i - N1 - N2; }
    else                       { s = s_wo; d = d_wo; j = i - N1 - 2 * N2; }
    float4 v = reinterpret_cast<const float4*>(s)[j];
    US4 h; h.a = f2h(v.x); h.b = f2h(v.y); h.c = f2h(v.z); h.d = f2h(v.w);
    reinterpret_cast<US4*>(d)[j] = h;
  }
}

// ---- encoders: f32 (B,R,C) -> f16 hi (B,R,C), f16 lo (B,R,C), f16 hi^T (B,C,R) ----
__global__ __launch_bounds__(256)
void k_conv_T(const float* __restrict__ src, u16* __restrict__ dh, u16* __restrict__ dl,
              u16* __restrict__ dt, int R, int C) {
  __shared__ u16 t[32][33];
  const int b = blockIdx.z;
  const float* s = src + (size_t)b * R * C;
  u16* dhb = dh + (size_t)b * R * C;
  u16* dlb = dl + (size_t)b * R * C;
  u16* dtb = dt + (size_t)b * R * C;
  const int c0 = blockIdx.x * 32, r0 = blockIdx.y * 32;
  const int tx = threadIdx.x, ty = threadIdx.y;
#pragma unroll
  for (int j = ty; j < 32; j += 8) {
    const size_t idx = (size_t)(r0 + j) * C + (c0 + tx);
    float x = s[idx];
    u16 h = f2h(x);
    dhb[idx] = h;
    dlb[idx] = f2h(x - h2f(h));
    t[j][tx] = h;
  }
  __syncthreads();
#pragma unroll
  for (int j = ty; j < 32; j += 8)
    dtb[(size_t)(c0 + j) * R + (r0 + tx)] = t[tx][j];
}

// ---- softmax (one wave per row): f32 in place + f16 copy ----
template<int L>
__global__ __launch_bounds__(256)
void k_softmax(float* __restrict__ io, u16* __restrict__ pb) {
  const int lane = threadIdx.x & 63;
  const size_t r = (size_t)blockIdx.x * 4 + (threadIdx.x >> 6);
  float* row = io + r * L;
  u16* prow = pb + r * L;
  constexpr int NV = L / 64;
  float v[NV];
  float mx = -3.4e38f;
#pragma unroll
  for (int j = 0; j < NV; ++j) { v[j] = row[lane + j * 64]; mx = fmaxf(mx, v[j]); }
#pragma unroll
  for (int s = 32; s; s >>= 1) mx = fmaxf(mx, __shfl_xor(mx, s));
  float sum = 0.f;
#pragma unroll
  for (int j = 0; j < NV; ++j) { v[j] = __expf(v[j] - mx); sum += v[j]; }
#pragma unroll
  for (int s = 32; s; s >>= 1) sum += __shfl_xor(sum, s);
  const float inv = 1.f / sum;
#pragma unroll
  for (int j = 0; j < NV; ++j) {
    float pv = v[j] * inv;
    row[lane + j * 64] = pv;
    prow[lane + j * 64] = f2h(pv);
  }
}

// ---- NT MFMA GEMM (m97 structure): C[m,n] = sum_k A[m,k]*B[n,k] ----
// SPLIT: 0 = 1-pass f16; 1 = A,B split hi/lo, 3 mfma (ah*bh + al*bh + ah*bl)
// A is 1-3 K-segments of segK (A0,A1,A2 consumed in order; SPLIT=1 only single-segment).
// EPI: 0 Cf=acc; 2 Cb=f16(acc); 6 Cb=f16(sigmoid(acc));
//      3 F += (1-G)*acc; 4 Cf = tanh(F + G*acc)   [G is f16]
constexpr int BM = 128, BN = 128, BK = 32;

template<int SPLIT, int EPI>
__global__ __launch_bounds__(256, 2)
void k_gemm_nt(const u16* __restrict__ A0, const u16* __restrict__ A1, const u16* __restrict__ A2,
               const u16* __restrict__ Alo,
               const u16* __restrict__ Bm, const u16* __restrict__ Blo,
               int lda, int ldb, long long sA, long long sB,
               float* __restrict__ Cf, u16* __restrict__ Cb, int ldc, long long sC,
               const u16* __restrict__ G, float* __restrict__ F,
               int K, int segK)
{
  __shared__ __align__(16) u16 sAh[BM * BK];
  __shared__ __align__(16) u16 sBh[BN * BK];
  __shared__ __align__(16) u16 sAl[SPLIT ? BM * BK : 8];
  __shared__ __align__(16) u16 sBl[SPLIT ? BN * BK : 8];

  const int tid = threadIdx.x;
  const int lane = tid & 63;
  const int wv = tid >> 6;
  const int wm = wv >> 1, wn = wv & 1;

  const long long b = blockIdx.z;
  const size_t aoff = (size_t)(b * sA) + (size_t)blockIdx.y * BM * lda;
  const size_t boff = (size_t)(b * sB) + (size_t)blockIdx.x * BN * ldb;

  // staging lane roles: 4 lanes per row, 16 rows per wave-chunk; lane i -> LDS +i*16B
  const int sr = lane >> 2;          // 0..15 sub-row within chunk
  const int sc = (lane & 3) * 8;     // elem offset within row

  u16* lAh0 = &sAh[(wv * 16) * BK];
  u16* lAh1 = &sAh[((wv + 4) * 16) * BK];
  u16* lBh0 = &sBh[(wv * 16) * BK];
  u16* lBh1 = &sBh[((wv + 4) * 16) * BK];

  f32x4 acc[16];
#pragma unroll
  for (int i = 0; i < 16; ++i) acc[i] = f32x4{0.f, 0.f, 0.f, 0.f};

  const int fr = lane & 15;
  const int kq = (lane >> 4) * 8;

  const u16* As = A0;
  int kl = 0;
  for (int k0 = 0; k0 < K; k0 += BK) {
    {
      const u16* ab = As + aoff + (size_t)sr * lda + kl + sc;
      const u16* bb = Bm + boff + (size_t)sr * ldb + k0 + sc;
      g2l16(ab + (size_t)(wv * 16) * lda, lAh0);
      g2l16(ab + (size_t)((wv + 4) * 16) * lda, lAh1);
      g2l16(bb + (size_t)(wv * 16) * ldb, lBh0);
      g2l16(bb + (size_t)((wv + 4) * 16) * ldb, lBh1);
    }
    if constexpr (SPLIT) {
      const u16* al = Alo + aoff + (size_t)sr * lda + kl + sc;
      const u16* bl = Blo + boff + (size_t)sr * ldb + k0 + sc;
      g2l16(al + (size_t)(wv * 16) * lda, &sAl[(wv * 16) * BK]);
      g2l16(al + (size_t)((wv + 4) * 16) * lda, &sAl[((wv + 4) * 16) * BK]);
      g2l16(bl + (size_t)(wv * 16) * ldb, &sBl[(wv * 16) * BK]);
      g2l16(bl + (size_t)((wv + 4) * 16) * ldb, &sBl[((wv + 4) * 16) * BK]);
    }
    __syncthreads();   // drains vmcnt -> LDS valid

    i32x4 ah[4], bh[4];
#pragma unroll
    for (int i = 0; i < 4; ++i) {
      ah[i] = *reinterpret_cast<const i32x4*>(&sAh[(wm * 64 + i * 16 + fr) * BK + kq]);
      bh[i] = *reinterpret_cast<const i32x4*>(&sBh[(wn * 64 + i * 16 + fr) * BK + kq]);
    }
    if constexpr (SPLIT) {
      i32x4 al[4], bl[4];
#pragma unroll
      for (int i = 0; i < 4; ++i) {
        al[i] = *reinterpret_cast<const i32x4*>(&sAl[(wm * 64 + i * 16 + fr) * BK + kq]);
        bl[i] = *reinterpret_cast<const i32x4*>(&sBl[(wn * 64 + i * 16 + fr) * BK + kq]);
      }
#pragma unroll
      for (int i = 0; i < 4; ++i)
#pragma unroll
        for (int j = 0; j < 4; ++j) {
          mfma_f16(acc[i * 4 + j], ah[i], bh[j]);
          mfma_f16(acc[i * 4 + j], al[i], bh[j]);
          mfma_f16(acc[i * 4 + j], ah[i], bl[j]);
        }
    } else {
#pragma unroll
      for (int i = 0; i < 4; ++i)
#pragma unroll
        for (int j = 0; j < 4; ++j)
          mfma_f16(acc[i * 4 + j], ah[i], bh[j]);
    }
    __syncthreads();   // before next-tile overwrite

    kl += BK;
    if (kl == segK) { kl = 0; As = (As == A0) ? A1 : A2; }
  }

  // epilogue: C/D layout col = lane&15, row = (lane>>4)*4 + reg
  const size_t cbse = (size_t)(b * sC);
  const int row0 = blockIdx.y * BM + wm * 64;
  const int col0 = blockIdx.x * BN + wn * 64;
  const int fq = (lane >> 4) * 4;
#pragma unroll
  for (int i = 0; i < 4; ++i) {
#pragma unroll
    for (int j = 0; j < 4; ++j) {
      f32x4 v = acc[i * 4 + j];
      const int c = col0 + j * 16 + fr;
#pragma unroll
      for (int q = 0; q < 4; ++q) {
        const int r = row0 + i * 16 + fq + q;
        const size_t idx = cbse + (size_t)r * ldc + c;
        if constexpr (EPI == 0) {
          Cf[idx] = v[q];
        } else if constexpr (EPI == 2) {
          Cb[idx] = f2h(v[q]);
        } else if constexpr (EPI == 6) {
          Cb[idx] = f2h(1.f / (1.f + __expf(-v[q])));
        } else if constexpr (EPI == 3) {
          F[idx] += (1.f - h2f(G[idx])) * v[q];
        } else {  // EPI == 4
          float x = F[idx] + h2f(G[idx]) * v[q];
          float ax = fabsf(x);
          float e = __expf(-2.f * ax);
          float t = (1.f - e) / (1.f + e);
          Cf[idx] = copysignf(t, x);
        }
      }
    }
  }
}

extern "C" void kernel_launch(void* const* d_in, const int* in_sizes, int n_in,
                              void* d_out, int out_size, void* d_ws, size_t ws_size,
                              hipStream_t stream) {
  (void)in_sizes; (void)n_in; (void)out_size; (void)ws_size;
  constexpr int B = 8, T = 1024, S = 1024, St = 512, H = 1024;
  constexpr long long BTH = (long long)B * T * H;
  constexpr long long BSH = (long long)B * S * H;
  constexpr long long BStH = (long long)B * St * H;
  constexpr long long BTS = (long long)B * T * S;
  constexpr long long BTSt = (long long)B * T * St;
  constexpr long long TH = (long long)T * H;

  const float* in_out  = (const float*)d_in[0];
  const float* in_sent = (const float*)d_in[1];
  const float* in_tmpl = (const float*)d_in[2];
  const float* in_Wg   = (const float*)d_in[3];
  const float* in_Ws   = (const float*)d_in[4];
  const float* in_Wt   = (const float*)d_in[5];
  const float* in_Wo   = (const float*)d_in[6];

  float* fus = (float*)d_out;         // (B,T,H)
  float* sw  = fus + BTH;             // (B,T,S)
  float* tw  = sw + BTS;              // (B,T,St)

  // ---- workspace (~197 MB) ----
  char* p = (char*)d_ws;
  auto take = [&](long long bytes) { char* q = p; p += bytes; return q; };
  u16* out_h   = (u16*)take(BTH * 2);
  u16* out_lo  = (u16*)take(BTH * 2);
  u16* sent_h  = (u16*)take(BSH * 2);    // dead after sent-logits -> reused as ctx_s
  u16* sent_lo = (u16*)take(BSH * 2);    // dead after sent-logits -> reused as ctx_t
  u16* tmpl_h  = (u16*)take(BStH * 2);
  u16* tmpl_lo = (u16*)take(BStH * 2);
  u16* sentT   = (u16*)take(BSH * 2);    // (B,H,S) f16 hi
  u16* tmplT   = (u16*)take(BStH * 2);   // (B,H,St) f16 hi
  u16* Wg_h    = (u16*)take((long long)3 * H * H * 2);
  u16* Ws_h    = (u16*)take((long long)H * H * 2);
  u16* Wt_h    = (u16*)take((long long)H * H * 2);
  u16* Wo_h    = (u16*)take((long long)H * H * 2);
  u16* Ps      = (u16*)take(BTS * 2);
  u16* Pt      = (u16*)take(BTSt * 2);
  u16* g16     = (u16*)take(BTH * 2);    // sigmoid(z) as f16
  float* F     = (float*)take(BTH * 4);

  u16* ctx_s = sent_h;    // written by PV-sent (sent_h/lo dead after sent-logits)
  u16* ctx_t = sent_lo;

  dim3 thr(256);

  // 1-4: conversions
  k_conv_hilo<<<2048, 256, 0, stream>>>(in_out, out_h, out_lo, (int)(BTH / 4));
  k_conv_w<<<1024, 256, 0, stream>>>(in_Wg, in_Ws, in_Wt, in_Wo, Wg_h, Ws_h, Wt_h, Wo_h);
  k_conv_T<<<dim3(H / 32, S / 32, B), dim3(32, 8), 0, stream>>>(in_sent, sent_h, sent_lo, sentT, S, H);
  k_conv_T<<<dim3(H / 32, St / 32, B), dim3(32, 8), 0, stream>>>(in_tmpl, tmpl_h, tmpl_lo, tmplT, St, H);

  // 5-6: logits (3-pass split f16) -> d_out weight slots
  k_gemm_nt<1, 0><<<dim3(S / BN, T / BM, B), thr, 0, stream>>>(
      out_h, nullptr, nullptr, out_lo, sent_h, sent_lo, H, H, TH, (long long)S * H,
      sw, nullptr, S, (long long)T * S, nullptr, nullptr, H, H);
  k_gemm_nt<1, 0><<<dim3(St / BN, T / BM, B), thr, 0, stream>>>(
      out_h, nullptr, nullptr, out_lo, tmpl_h, tmpl_lo, H, H, TH, (long long)St * H,
      tw, nullptr, St, (long long)T * St, nullptr, nullptr, H, H);

  // 7-8: softmax in place + f16 copy
  k_softmax<1024><<<(B * T) / 4, 256, 0, stream>>>(sw, Ps);
  k_softmax<512><<<(B * T) / 4, 256, 0, stream>>>(tw, Pt);

  // 9-10: PV -> ctx (f16)
  k_gemm_nt<0, 2><<<dim3(H / BN, T / BM, B), thr, 0, stream>>>(
      Ps, nullptr, nullptr, nullptr, sentT, nullptr, S, S, (long long)T * S, (long long)H * S,
      nullptr, ctx_s, H, TH, nullptr, nullptr, S, S);
  k_gemm_nt<0, 2><<<dim3(H / BN, T / BM, B), thr, 0, stream>>>(
      Pt, nullptr, nullptr, nullptr, tmplT, nullptr, St, St, (long long)T * St, (long long)H * St,
      nullptr, ctx_t, H, TH, nullptr, nullptr, St, St);

  // 11: g = sigmoid(cat @ Wg^T) as f16, single K=3072 GEMM over 3 A-segments
  k_gemm_nt<0, 6><<<dim3(H / BN, (B * T) / BM, 1), thr, 0, stream>>>(
      ctx_s, ctx_t, out_h, nullptr, Wg_h, nullptr, H, 3 * H, 0LL, 0LL,
      nullptr, g16, H, 0LL, nullptr, nullptr, 3 * H, H);

  // 12: F = output @ Wo^T
  k_gemm_nt<0, 0><<<dim3(H / BN, (B * T) / BM, 1), thr, 0, stream>>>(
      out_h, nullptr, nullptr, nullptr, Wo_h, nullptr, H, H, 0LL, 0LL,
      F, nullptr, H, 0LL, nullptr, nullptr, H, H);
  // 13: F += (1-g) * (sent_ctx @ Ws^T)
  k_gemm_nt<0, 3><<<dim3(H / BN, (B * T) / BM, 1), thr, 0, stream>>>(
      ctx_s, nullptr, nullptr, nullptr, Ws_h, nullptr, H, H, 0LL, 0LL,
      nullptr, nullptr, H, 0LL, g16, F, H, H);
  // 14: fusion = tanh(F + g * (tmpl_ctx @ Wt^T)) -> d_out
  k_gemm_nt<0, 4><<<dim3(H / BN, (B * T) / BM, 1), thr, 0, stream>>>(
      ctx_t, nullptr, nullptr, nullptr, Wt_h, nullptr, H, H, 0LL, 0LL,
      fus, nullptr, H, 0LL, g16, F, H, H);
}

// Round 6
// 407.818 us; speedup vs baseline: 1.3320x; 1.0709x over previous
//
#include <hip/hip_runtime.h>
#include <stdint.h>

typedef unsigned short u16;
typedef float f32x4 __attribute__((ext_vector_type(4)));
typedef int   i32x4 __attribute__((ext_vector_type(4)));

__device__ __forceinline__ u16 f2h(float f) {
  _Float16 h = (_Float16)f;  // v_cvt_f16_f32, RNE
  u16 u; __builtin_memcpy(&u, &h, 2); return u;
}
__device__ __forceinline__ float h2f(u16 u) {
  _Float16 h; __builtin_memcpy(&h, &u, 2); return (float)h;
}

__device__ __forceinline__ void mfma_f16(f32x4& c, i32x4 a, i32x4 b) {
  asm("v_mfma_f32_16x16x32_f16 %0, %1, %2, %0" : "+v"(c) : "v"(a), "v"(b));
}

// async global->LDS, 16B/lane; LDS dest = wave-uniform base, lane i lands at +i*16B
__device__ __forceinline__ void g2l16(const u16* g, u16* l) {
  __builtin_amdgcn_global_load_lds((const __attribute__((address_space(1))) void*)g,
                                   (__attribute__((address_space(3))) void*)l,
                                   16, 0, 0);
}

// bijective XCD-chunk swizzle (requires gridDim product % 8 == 0; all our grids qualify)
__device__ __forceinline__ void xcd_swz(int& bx, int& by, int& bz) {
  const int gx = gridDim.x, gy = gridDim.y;
  const int n = gx * gy * gridDim.z;
  const int lin = blockIdx.x + gx * (blockIdx.y + gy * blockIdx.z);
  const int q = n >> 3;
  const int s = (lin & 7) * q + (lin >> 3);
  bx = s % gx;
  const int t = s / gx;
  by = t % gy;
  bz = t / gy;
}

struct alignas(8) US4 { u16 a, b, c, d; };

// ---- output: f32 -> f16 hi + lo residual ----
__global__ void k_conv_hilo(const float* __restrict__ src, u16* __restrict__ hi,
                            u16* __restrict__ lo, int n4) {
  int i = blockIdx.x * blockDim.x + threadIdx.x;
  int stride = gridDim.x * blockDim.x;
  for (; i < n4; i += stride) {
    float4 v = reinterpret_cast<const float4*>(src)[i];
    US4 h, l;
    h.a = f2h(v.x); l.a = f2h(v.x - h2f(h.a));
    h.b = f2h(v.y); l.b = f2h(v.y - h2f(h.b));
    h.c = f2h(v.z); l.c = f2h(v.z - h2f(h.c));
    h.d = f2h(v.w); l.d = f2h(v.w - h2f(h.d));
    reinterpret_cast<US4*>(hi)[i] = h;
    reinterpret_cast<US4*>(lo)[i] = l;
  }
}

// ---- 4 weight matrices: f32 -> f16 ----
__global__ void k_conv_w(const float* __restrict__ s_wg, const float* __restrict__ s_ws,
                         const float* __restrict__ s_wt, const float* __restrict__ s_wo,
                         u16* __restrict__ d_wg, u16* __restrict__ d_ws,
                         u16* __restrict__ d_wt, u16* __restrict__ d_wo) {
  constexpr int N1 = 786432;   // 3*1024*1024/4
  constexpr int N2 = 262144;   // 1024*1024/4
  constexpr int total = N1 + 3 * N2;
  int i = blockIdx.x * blockDim.x + threadIdx.x;
  int stride = gridDim.x * blockDim.x;
  for (; i < total; i += stride) {
    const float* s; u16* d; int j;
    if (i < N1)                { s = s_wg; d = d_wg; j = i; }
    else if (i < N1 + N2)      { s = s_ws; d = d_ws; j = i - N1; }
    else if (i < N1 + 2 * N2)  { s = s_wt; d = d_wt; j = i - N1 - N2; }
    else                       { s = s_wo; d = d_wo; j = i - N1 - 2 * N2; }
    float4 v = reinterpret_cast<const float4*>(s)[j];
    US4 h; h.a = f2h(v.x); h.b = f2h(v.y); h.c = f2h(v.z); h.d = f2h(v.w);
    reinterpret_cast<US4*>(d)[j] = h;
  }
}

// ---- encoders: f32 (B,R,C) -> f16 hi, f16 lo, f16 hi^T (B,C,R) ----
__global__ __launch_bounds__(256)
void k_conv_T(const float* __restrict__ src, u16* __restrict__ dh, u16* __restrict__ dl,
              u16* __restrict__ dt, int R, int C) {
  __shared__ u16 t[32][33];
  const int b = blockIdx.z;
  const float* s = src + (size_t)b * R * C;
  u16* dhb = dh + (size_t)b * R * C;
  u16* dlb = dl + (size_t)b * R * C;
  u16* dtb = dt + (size_t)b * R * C;
  const int c0 = blockIdx.x * 32, r0 = blockIdx.y * 32;
  const int tx = threadIdx.x, ty = threadIdx.y;
#pragma unroll
  for (int j = ty; j < 32; j += 8) {
    const size_t idx = (size_t)(r0 + j) * C + (c0 + tx);
    float x = s[idx];
    u16 h = f2h(x);
    dhb[idx] = h;
    dlb[idx] = f2h(x - h2f(h));
    t[j][tx] = h;
  }
  __syncthreads();
#pragma unroll
  for (int j = ty; j < 32; j += 8)
    dtb[(size_t)(c0 + j) * R + (r0 + tx)] = t[tx][j];
}

// ---- softmax (one wave per row): f32 in place + f16 copy ----
template<int L>
__global__ __launch_bounds__(256)
void k_softmax(float* __restrict__ io, u16* __restrict__ pb) {
  const int lane = threadIdx.x & 63;
  const size_t r = (size_t)blockIdx.x * 4 + (threadIdx.x >> 6);
  float* row = io + r * L;
  u16* prow = pb + r * L;
  constexpr int NV = L / 64;
  float v[NV];
  float mx = -3.4e38f;
#pragma unroll
  for (int j = 0; j < NV; ++j) { v[j] = row[lane + j * 64]; mx = fmaxf(mx, v[j]); }
#pragma unroll
  for (int s = 32; s; s >>= 1) mx = fmaxf(mx, __shfl_xor(mx, s));
  float sum = 0.f;
#pragma unroll
  for (int j = 0; j < NV; ++j) { v[j] = __expf(v[j] - mx); sum += v[j]; }
#pragma unroll
  for (int s = 32; s; s >>= 1) sum += __shfl_xor(sum, s);
  const float inv = 1.f / sum;
#pragma unroll
  for (int j = 0; j < NV; ++j) {
    float pv = v[j] * inv;
    row[lane + j * 64] = pv;
    prow[lane + j * 64] = f2h(pv);
  }
}

// ================= GEMM core =================
constexpr int BM = 128, BN = 128, BK = 32;

struct TC { int wv, sr, sc, wm, wn, fr, kq; };

__device__ __forceinline__ TC make_tc(int tid) {
  TC t;
  const int lane = tid & 63;
  t.wv = tid >> 6;
  t.sr = lane >> 2;
  t.sc = (lane & 3) * 8;
  t.wm = t.wv >> 1;
  t.wn = t.wv & 1;
  t.fr = lane & 15;
  t.kq = (lane >> 4) * 8;
  return t;
}

// 2-phase double-buffered NT pass: acc += A(0:128, 0:K) * B(0:128, 0:K)^T
// sA/sB (and sAl/sBl when SPLIT) are 2*BM*BK double-buffers.
template<int SPLIT>
__device__ __forceinline__ void gemm_pass(
    f32x4 (&acc)[16],
    const u16* __restrict__ A, const u16* __restrict__ Al, int lda,
    const u16* __restrict__ B, const u16* __restrict__ Bl, int ldb,
    int K, u16* sA, u16* sAl, u16* sB, u16* sBl, const TC& t)
{
  const int nt = K / BK;
  auto stage = [&](int c, int k0) {
    u16* dA = sA + c * (BM * BK);
    u16* dB = sB + c * (BN * BK);
    const u16* ar = A + (size_t)t.sr * lda + k0 + t.sc;
    const u16* br = B + (size_t)t.sr * ldb + k0 + t.sc;
    g2l16(ar + (size_t)(t.wv * 16) * lda, dA + (t.wv * 16) * BK);
    g2l16(ar + (size_t)((t.wv + 4) * 16) * lda, dA + ((t.wv + 4) * 16) * BK);
    g2l16(br + (size_t)(t.wv * 16) * ldb, dB + (t.wv * 16) * BK);
    g2l16(br + (size_t)((t.wv + 4) * 16) * ldb, dB + ((t.wv + 4) * 16) * BK);
    if constexpr (SPLIT) {
      u16* dAl = sAl + c * (BM * BK);
      u16* dBl = sBl + c * (BN * BK);
      const u16* alr = Al + (size_t)t.sr * lda + k0 + t.sc;
      const u16* blr = Bl + (size_t)t.sr * ldb + k0 + t.sc;
      g2l16(alr + (size_t)(t.wv * 16) * lda, dAl + (t.wv * 16) * BK);
      g2l16(alr + (size_t)((t.wv + 4) * 16) * lda, dAl + ((t.wv + 4) * 16) * BK);
      g2l16(blr + (size_t)(t.wv * 16) * ldb, dBl + (t.wv * 16) * BK);
      g2l16(blr + (size_t)((t.wv + 4) * 16) * ldb, dBl + ((t.wv + 4) * 16) * BK);
    }
  };

  stage(0, 0);
  __syncthreads();           // tile 0 resident
  int c = 0;
  for (int it = 0; it < nt; ++it) {
    if (it + 1 < nt) stage(c ^ 1, (it + 1) * BK);   // async, overlaps MFMA below
    const u16* bA = sA + c * (BM * BK);
    const u16* bB = sB + c * (BN * BK);
    i32x4 ah[4], bh[4];
#pragma unroll
    for (int i = 0; i < 4; ++i) {
      ah[i] = *reinterpret_cast<const i32x4*>(&bA[(t.wm * 64 + i * 16 + t.fr) * BK + t.kq]);
      bh[i] = *reinterpret_cast<const i32x4*>(&bB[(t.wn * 64 + i * 16 + t.fr) * BK + t.kq]);
    }
    if constexpr (SPLIT) {
      const u16* bAl = sAl + c * (BM * BK);
      const u16* bBl = sBl + c * (BN * BK);
      i32x4 al[4], bl[4];
#pragma unroll
      for (int i = 0; i < 4; ++i) {
        al[i] = *reinterpret_cast<const i32x4*>(&bAl[(t.wm * 64 + i * 16 + t.fr) * BK + t.kq]);
        bl[i] = *reinterpret_cast<const i32x4*>(&bBl[(t.wn * 64 + i * 16 + t.fr) * BK + t.kq]);
      }
#pragma unroll
      for (int i = 0; i < 4; ++i)
#pragma unroll
        for (int j = 0; j < 4; ++j) {
          mfma_f16(acc[i * 4 + j], ah[i], bh[j]);
          mfma_f16(acc[i * 4 + j], al[i], bh[j]);
          mfma_f16(acc[i * 4 + j], ah[i], bl[j]);
        }
    } else {
#pragma unroll
      for (int i = 0; i < 4; ++i)
#pragma unroll
        for (int j = 0; j < 4; ++j)
          mfma_f16(acc[i * 4 + j], ah[i], bh[j]);
    }
    __syncthreads();         // drains next-tile loads (vmcnt0) + read/write fence
    c ^= 1;
  }
}

// ---- generic NT GEMM kernel ----
// A consumed as nseg segments of segK (A0,A1,A2); B k-index advances globally.
// EPI: 0 Cf=acc (f32); 2 Cb=f16(acc); 6 Cb=f16(sigmoid(acc))
template<int SPLIT, int EPI>
__global__ __launch_bounds__(256, 2)
void k_gemm_nt(const u16* __restrict__ A0, const u16* __restrict__ A1, const u16* __restrict__ A2,
               const u16* __restrict__ Alo,
               const u16* __restrict__ Bm, const u16* __restrict__ Blo,
               int lda, int ldb, long long strA, long long strB,
               float* __restrict__ Cf, u16* __restrict__ Cb, int ldc, long long strC,
               int segK, int nseg)
{
  __shared__ __align__(16) u16 sA[2 * BM * BK];
  __shared__ __align__(16) u16 sB[2 * BN * BK];
  __shared__ __align__(16) u16 sAl[SPLIT ? 2 * BM * BK : 8];
  __shared__ __align__(16) u16 sBl[SPLIT ? 2 * BN * BK : 8];

  int bx, by, bz;
  xcd_swz(bx, by, bz);
  const TC t = make_tc(threadIdx.x);

  const size_t aoff = (size_t)((long long)bz * strA) + (size_t)by * BM * lda;
  const size_t boff = (size_t)((long long)bz * strB) + (size_t)bx * BN * ldb;

  f32x4 acc[16];
#pragma unroll
  for (int i = 0; i < 16; ++i) acc[i] = f32x4{0.f, 0.f, 0.f, 0.f};

  const u16* As[3] = {A0, A1, A2};
  for (int s = 0; s < nseg; ++s) {
    gemm_pass<SPLIT>(acc, As[s] + aoff, SPLIT ? Alo + aoff : nullptr, lda,
                     Bm + boff + (size_t)s * segK, SPLIT ? Blo + boff : nullptr, ldb,
                     segK, sA, sAl, sB, sBl, t);
  }

  // epilogue: C/D layout col = lane&15, row = (lane>>4)*4 + reg
  const size_t cbse = (size_t)((long long)bz * strC);
  const int row0 = by * BM + t.wm * 64;
  const int col0 = bx * BN + t.wn * 64;
  const int fq = ((threadIdx.x & 63) >> 4) * 4;
#pragma unroll
  for (int i = 0; i < 4; ++i) {
#pragma unroll
    for (int j = 0; j < 4; ++j) {
      f32x4 v = acc[i * 4 + j];
      const int c = col0 + j * 16 + t.fr;
#pragma unroll
      for (int q = 0; q < 4; ++q) {
        const int r = row0 + i * 16 + fq + q;
        const size_t idx = cbse + (size_t)r * ldc + c;
        if constexpr (EPI == 0) {
          Cf[idx] = v[q];
        } else if constexpr (EPI == 2) {
          Cb[idx] = f2h(v[q]);
        } else {  // EPI == 6
          Cb[idx] = f2h(1.f / (1.f + __expf(-v[q])));
        }
      }
    }
  }
}

// ---- fused fusion kernel: tanh((1-g)*S + g*T + O) with S,T,O chained in registers ----
__global__ __launch_bounds__(256, 2)
void k_fusion(const u16* __restrict__ ctx_s, const u16* __restrict__ ctx_t,
              const u16* __restrict__ outh,
              const u16* __restrict__ Ws, const u16* __restrict__ Wt,
              const u16* __restrict__ Wo,
              const u16* __restrict__ g16, float* __restrict__ fus)
{
  constexpr int H = 1024;
  __shared__ __align__(16) u16 sA[2 * BM * BK];
  __shared__ __align__(16) u16 sB[2 * BN * BK];

  int bx, by, bz;
  xcd_swz(bx, by, bz);
  const TC t = make_tc(threadIdx.x);

  const size_t aoff = (size_t)by * BM * H;
  const size_t boff = (size_t)bx * BN * H;

  const int row0 = by * BM + t.wm * 64;
  const int col0 = bx * BN + t.wn * 64;
  const int fq = ((threadIdx.x & 63) >> 4) * 4;

  f32x4 acc[16];
#pragma unroll
  for (int i = 0; i < 16; ++i) acc[i] = f32x4{0.f, 0.f, 0.f, 0.f};

  // pass 1: S = ctx_s @ Ws^T
  gemm_pass<0>(acc, ctx_s + aoff, nullptr, H, Ws + boff, nullptr, H, H,
               sA, nullptr, sB, nullptr, t);
  f32x4 S[16];
#pragma unroll
  for (int i = 0; i < 16; ++i) { S[i] = acc[i]; acc[i] = f32x4{0.f, 0.f, 0.f, 0.f}; }

  // pass 2: T = ctx_t @ Wt^T, then S = S + g*(T - S)
  gemm_pass<0>(acc, ctx_t + aoff, nullptr, H, Wt + boff, nullptr, H, H,
               sA, nullptr, sB, nullptr, t);
#pragma unroll
  for (int i = 0; i < 4; ++i) {
#pragma unroll
    for (int j = 0; j < 4; ++j) {
      const int c = col0 + j * 16 + t.fr;
#pragma unroll
      for (int q = 0; q < 4; ++q) {
        const int r = row0 + i * 16 + fq + q;
        const float gv = h2f(g16[(size_t)r * H + c]);
        const float sv = S[i * 4 + j][q];
        S[i * 4 + j][q] = sv + gv * (acc[i * 4 + j][q] - sv);
      }
    }
  }
#pragma unroll
  for (int i = 0; i < 16; ++i) acc[i] = f32x4{0.f, 0.f, 0.f, 0.f};

  // pass 3: O = outh @ Wo^T, then write tanh(S + O)
  gemm_pass<0>(acc, outh + aoff, nullptr, H, Wo + boff, nullptr, H, H,
               sA, nullptr, sB, nullptr, t);
#pragma unroll
  for (int i = 0; i < 4; ++i) {
#pragma unroll
    for (int j = 0; j < 4; ++j) {
      const int c = col0 + j * 16 + t.fr;
#pragma unroll
      for (int q = 0; q < 4; ++q) {
        const int r = row0 + i * 16 + fq + q;
        float x = S[i * 4 + j][q] + acc[i * 4 + j][q];
        float ax = fabsf(x);
        float e = __expf(-2.f * ax);
        float th = (1.f - e) / (1.f + e);
        fus[(size_t)r * H + c] = copysignf(th, x);
      }
    }
  }
}

extern "C" void kernel_launch(void* const* d_in, const int* in_sizes, int n_in,
                              void* d_out, int out_size, void* d_ws, size_t ws_size,
                              hipStream_t stream) {
  (void)in_sizes; (void)n_in; (void)out_size; (void)ws_size;
  constexpr int B = 8, T = 1024, S = 1024, St = 512, H = 1024;
  constexpr long long BTH = (long long)B * T * H;
  constexpr long long BSH = (long long)B * S * H;
  constexpr long long BStH = (long long)B * St * H;
  constexpr long long BTS = (long long)B * T * S;
  constexpr long long BTSt = (long long)B * T * St;
  constexpr long long TH = (long long)T * H;

  const float* in_out  = (const float*)d_in[0];
  const float* in_sent = (const float*)d_in[1];
  const float* in_tmpl = (const float*)d_in[2];
  const float* in_Wg   = (const float*)d_in[3];
  const float* in_Ws   = (const float*)d_in[4];
  const float* in_Wt   = (const float*)d_in[5];
  const float* in_Wo   = (const float*)d_in[6];

  float* fus = (float*)d_out;         // (B,T,H)
  float* sw  = fus + BTH;             // (B,T,S)
  float* tw  = sw + BTS;              // (B,T,St)

  // ---- workspace ----
  char* p = (char*)d_ws;
  auto take = [&](long long bytes) { char* q = p; p += bytes; return q; };
  u16* out_h   = (u16*)take(BTH * 2);
  u16* out_lo  = (u16*)take(BTH * 2);
  u16* sent_h  = (u16*)take(BSH * 2);    // dead after sent-logits -> reused as ctx_s
  u16* sent_lo = (u16*)take(BSH * 2);    // dead after sent-logits -> reused as ctx_t
  u16* tmpl_h  = (u16*)take(BStH * 2);
  u16* tmpl_lo = (u16*)take(BStH * 2);
  u16* sentT   = (u16*)take(BSH * 2);    // (B,H,S)
  u16* tmplT   = (u16*)take(BStH * 2);   // (B,H,St)
  u16* Wg_h    = (u16*)take((long long)3 * H * H * 2);
  u16* Ws_h    = (u16*)take((long long)H * H * 2);
  u16* Wt_h    = (u16*)take((long long)H * H * 2);
  u16* Wo_h    = (u16*)take((long long)H * H * 2);
  u16* Ps      = (u16*)take(BTS * 2);
  u16* Pt      = (u16*)take(BTSt * 2);
  u16* g16     = (u16*)take(BTH * 2);    // sigmoid(z) f16

  u16* ctx_s = sent_h;
  u16* ctx_t = sent_lo;

  dim3 thr(256);

  // conversions
  k_conv_hilo<<<2048, 256, 0, stream>>>(in_out, out_h, out_lo, (int)(BTH / 4));
  k_conv_w<<<1024, 256, 0, stream>>>(in_Wg, in_Ws, in_Wt, in_Wo, Wg_h, Ws_h, Wt_h, Wo_h);
  k_conv_T<<<dim3(H / 32, S / 32, B), dim3(32, 8), 0, stream>>>(in_sent, sent_h, sent_lo, sentT, S, H);
  k_conv_T<<<dim3(H / 32, St / 32, B), dim3(32, 8), 0, stream>>>(in_tmpl, tmpl_h, tmpl_lo, tmplT, St, H);

  // logits (3-pass split f16) -> d_out weight slots
  k_gemm_nt<1, 0><<<dim3(S / BN, T / BM, B), thr, 0, stream>>>(
      out_h, nullptr, nullptr, out_lo, sent_h, sent_lo, H, H, TH, (long long)S * H,
      sw, nullptr, S, (long long)T * S, H, 1);
  k_gemm_nt<1, 0><<<dim3(St / BN, T / BM, B), thr, 0, stream>>>(
      out_h, nullptr, nullptr, out_lo, tmpl_h, tmpl_lo, H, H, TH, (long long)St * H,
      tw, nullptr, St, (long long)T * St, H, 1);

  // softmax in place + f16 copy
  k_softmax<1024><<<(B * T) / 4, 256, 0, stream>>>(sw, Ps);
  k_softmax<512><<<(B * T) / 4, 256, 0, stream>>>(tw, Pt);

  // PV -> ctx (f16)
  k_gemm_nt<0, 2><<<dim3(H / BN, T / BM, B), thr, 0, stream>>>(
      Ps, nullptr, nullptr, nullptr, sentT, nullptr, S, S, (long long)T * S, (long long)H * S,
      nullptr, ctx_s, H, TH, S, 1);
  k_gemm_nt<0, 2><<<dim3(H / BN, T / BM, B), thr, 0, stream>>>(
      Pt, nullptr, nullptr, nullptr, tmplT, nullptr, St, St, (long long)T * St, (long long)H * St,
      nullptr, ctx_t, H, TH, St, 1);

  // gate = sigmoid(cat @ Wg^T) as f16, K=3072 via 3 A-segments
  k_gemm_nt<0, 6><<<dim3(H / BN, (B * T) / BM, 1), thr, 0, stream>>>(
      ctx_s, ctx_t, out_h, nullptr, Wg_h, nullptr, H, 3 * H, 0LL, 0LL,
      nullptr, g16, H, 0LL, H, 3);

  // fused fusion: tanh((1-g)*ctx_s@Ws + g*ctx_t@Wt + out@Wo) -> d_out
  k_fusion<<<dim3(H / BN, (B * T) / BM, 1), thr, 0, stream>>>(
      ctx_s, ctx_t, out_h, Ws_h, Wt_h, Wo_h, g16, fus);
}